// Round 11
// baseline (238.102 us; speedup 1.0000x reference)
//
#include <hip/hip_runtime.h>
#include <hip/hip_fp16.h>
#include <stdint.h>

#define NN    100000
#define FIN   128
#define HIDN  64
#define NCLS  40
#define NE    1600000
#define NPB   128                     // nodes per bucket
#define BSHIFT 7
#define NBUCK ((NN + NPB - 1) / NPB)  // 782 buckets of 128 nodes
#define EPB   2048                    // edges per partition block
#define NEB   ((NE + EPB - 1) / EPB)  // 782 partition blocks

typedef unsigned int uint32;
typedef __attribute__((ext_vector_type(8))) short short8v;
typedef __attribute__((ext_vector_type(4))) float f32x4;

static __device__ __forceinline__ unsigned short f2bf(float f) {
  uint32 u = __float_as_uint(f);
  u = (u + 0x7fffu + ((u >> 16) & 1u)) >> 16;   // RNE
  return (unsigned short)u;
}
static __device__ __forceinline__ uint32 pack2(float lo, float hi) {
  return (uint32)f2bf(lo) | ((uint32)f2bf(hi) << 16);
}
static __device__ __forceinline__ float bf_lo(uint32 v) {
  return __uint_as_float(v << 16);
}
static __device__ __forceinline__ float bf_hi(uint32 v) {
  return __uint_as_float(v & 0xFFFF0000u);
}
static __device__ __forceinline__ float2 h2f2(uint32 w) {
  __half2 h = __builtin_bit_cast(__half2, w);
  return __half22float2(h);
}
static __device__ __forceinline__ f32x4 mfma_bf16(uint4 a, uint4 b, f32x4 c) {
  short8v av = __builtin_bit_cast(short8v, a);
  short8v bv = __builtin_bit_cast(short8v, b);
  return __builtin_amdgcn_mfma_f32_16x16x32_bf16(av, bv, c, 0, 0, 0);
}

// permuted hs/g column map: float index z in [0,64) -> true column.
static __device__ __forceinline__ int perm_col(int z) {
  return 4 * (z >> 3) + ((z & 7) >> 1) + 16 * (z & 1) + ((z >= 32) ? 16 : 0);
}

// accumulate 8 bf16 lanes of a uint4 into a[8]
#define ACC8(v)                                                              \
  do {                                                                       \
    a[0] += bf_lo((v).x); a[1] += bf_hi((v).x);                              \
    a[2] += bf_lo((v).y); a[3] += bf_hi((v).y);                              \
    a[4] += bf_lo((v).z); a[5] += bf_hi((v).z);                              \
    a[6] += bf_lo((v).w); a[7] += bf_hi((v).w);                              \
  } while (0)

// accumulate 8 fp16 lanes of a uint4 into a[8]
#define ACC8H(v)                                                             \
  do {                                                                       \
    float2 f0 = h2f2((v).x), f1 = h2f2((v).y);                               \
    float2 f2 = h2f2((v).z), f3 = h2f2((v).w);                               \
    a[0] += f0.x; a[1] += f0.y; a[2] += f1.x; a[3] += f1.y;                  \
    a[4] += f2.x; a[5] += f2.y; a[6] += f3.x; a[7] += f3.y;                  \
  } while (0)

// ---- wfrag+probe (merged): W1 frags (blocks 0..31), W2 frags split hi/lo
// (blocks 32..43), probe+b1p (block 44). ----
__global__ __launch_bounds__(64) void wfrag_kernel(const float* __restrict__ W,
                                                   const float* __restrict__ b1,
                                                   const float* __restrict__ W2,
                                                   const unsigned int* __restrict__ raw,
                                                   uint4* __restrict__ wfrag,
                                                   uint4* __restrict__ w2frag,
                                                   float* __restrict__ b1p,
                                                   int* __restrict__ flag) {
  int bk = blockIdx.x;
  int tid = threadIdx.x;
  if (bk < 32) {
    // W1[128][64] -> MFMA B-frag order, split hi/lo bf16.
    // frag idx = ((t*4 + kr)*4 + nr)*64 + lane
    int idx = bk * 64 + tid;
    int lane = idx & 63;
    int nr = (idx >> 6) & 3;
    int kr = (idx >> 8) & 3;
    int t  = idx >> 10;                        // 0 = hi, 1 = lo
    int n  = nr * 16 + (lane & 15);
    int k0 = kr * 32 + (lane >> 4) * 8;
    uint32 w[4];
#pragma unroll
    for (int j = 0; j < 4; ++j) {
      float a = W[(k0 + 2 * j) * HIDN + n];
      float b = W[(k0 + 2 * j + 1) * HIDN + n];
      uint32 ha = f2bf(a), hb = f2bf(b);
      if (t == 0) {
        w[j] = ha | (hb << 16);
      } else {
        float ra = a - __uint_as_float(ha << 16);
        float rb = b - __uint_as_float(hb << 16);
        w[j] = (uint32)f2bf(ra) | ((uint32)f2bf(rb) << 16);
      }
    }
    wfrag[idx] = make_uint4(w[0], w[1], w[2], w[3]);
  } else if (bk < 44) {
    // W2p[z][c] = W2[perm_col(z)][c] -> B-frags for gemm2 (K=64, N=48 pad).
    int f = bk - 32;                 // 0..11 = t2*6 + kr*3 + nf
    int t2 = f / 6;
    int kr = (f / 3) % 2;
    int nf = f % 3;
    int c  = nf * 16 + (tid & 15);
    int k0 = kr * 32 + (tid >> 4) * 8;
    uint32 w[4];
#pragma unroll
    for (int j = 0; j < 4; ++j) {
      float a = (c < NCLS) ? W2[perm_col(k0 + 2 * j) * NCLS + c] : 0.f;
      float b = (c < NCLS) ? W2[perm_col(k0 + 2 * j + 1) * NCLS + c] : 0.f;
      uint32 ha = f2bf(a), hb = f2bf(b);
      if (t2 == 0) {
        w[j] = ha | (hb << 16);
      } else {
        float ra = a - __uint_as_float(ha << 16);
        float rb = b - __uint_as_float(hb << 16);
        w[j] = (uint32)f2bf(ra) | ((uint32)f2bf(rb) << 16);
      }
    }
    w2frag[f * 64 + tid] = make_uint4(w[0], w[1], w[2], w[3]);
  } else {
    b1p[tid] = b1[perm_col(tid)];
    if (tid == 0) {
      int is64 = 1;
      for (int i = 0; i < 64; ++i)
        if (raw[2 * i + 1] != 0u) { is64 = 0; break; }
      *flag = is64;
    }
  }
}

// ---- passA (R11: EPB 2048, 782 blocks = 3/CU): per-block bucket histogram ----
__global__ __launch_bounds__(256) void passA_kernel(const void* __restrict__ eptr,
                                                    const int* __restrict__ flag,
                                                    int* __restrict__ mat) {
  __shared__ int cnt[NBUCK];
  int tid = threadIdx.x;
  for (int i = tid; i < NBUCK; i += 256) cnt[i] = 0;
  __syncthreads();
  int is64 = *flag;
  int base = blockIdx.x * EPB;
#pragma unroll
  for (int k = 0; k < EPB / 256; ++k) {
    int e = base + k * 256 + tid;
    if (e < NE) {
      int d = is64 ? (int)((const long long*)eptr)[e + NE]
                   : ((const int*)eptr)[e + NE];
      atomicAdd(&cnt[d >> BSHIFT], 1);
    }
  }
  __syncthreads();
  for (int i = tid; i < NBUCK; i += 256)
    mat[blockIdx.x * NBUCK + i] = cnt[i];
}

// ---- passB1 (R11: 1024-thr scan over NEB=782 blocks per bucket) ----
__global__ __launch_bounds__(1024) void passB1_kernel(int* __restrict__ mat,
                                                      int* __restrict__ tot) {
  __shared__ int s[1024];
  int b = blockIdx.x;         // bucket
  int t = threadIdx.x;        // block index
  int v = (t < NEB) ? mat[t * NBUCK + b] : 0;
  s[t] = v;
  __syncthreads();
#pragma unroll
  for (int d = 1; d < 1024; d <<= 1) {
    int u = (t >= d) ? s[t - d] : 0;
    __syncthreads();
    s[t] += u;
    __syncthreads();
  }
  if (t < NEB) mat[t * NBUCK + b] = s[t] - v;  // exclusive prefix within bucket
  if (t == 1023) tot[b] = s[1023];
}

// ---- passB2 (R11: 1024-thr scan of NBUCK=782 totals) ----
__global__ __launch_bounds__(1024) void passB2_kernel(const int* __restrict__ tot,
                                                      int* __restrict__ bbase) {
  __shared__ int s[1024];
  int i = threadIdx.x;
  int v = (i < NBUCK) ? tot[i] : 0;
  s[i] = v;
  __syncthreads();
#pragma unroll
  for (int d = 1; d < 1024; d <<= 1) {
    int u = (i >= d) ? s[i - d] : 0;
    __syncthreads();
    s[i] += u;
    __syncthreads();
  }
  if (i < NBUCK) bbase[i] = s[i] - v;
  if (i == 1023) bbase[NBUCK] = s[1023];
}

// ---- passC (R11: 782 blocks): place edges into bucket-sorted bbuf ----
// bbuf word = src (17 bits) | node-local id (7 bits) << 17.
__global__ __launch_bounds__(256) void passC_kernel(const void* __restrict__ eptr,
                                                    const int* __restrict__ flag,
                                                    const int* __restrict__ mat,
                                                    const int* __restrict__ bbase,
                                                    uint32* __restrict__ bbuf) {
  __shared__ int cur[NBUCK];
  int tid = threadIdx.x;
  for (int i = tid; i < NBUCK; i += 256)
    cur[i] = bbase[i] + mat[blockIdx.x * NBUCK + i];
  __syncthreads();
  int is64 = *flag;
  int base = blockIdx.x * EPB;
#pragma unroll
  for (int k = 0; k < EPB / 256; ++k) {
    int e = base + k * 256 + tid;
    if (e < NE) {
      int s, d;
      if (is64) {
        const long long* p = (const long long*)eptr;
        s = (int)p[e]; d = (int)p[e + NE];
      } else {
        const int* p = (const int*)eptr;
        s = p[e]; d = p[e + NE];
      }
      int slot = atomicAdd(&cur[d >> BSHIFT], 1);
      bbuf[slot] = (uint32)s | ((uint32)(d & (NPB - 1)) << 17);
    }
  }
}

// ---- build (R11: 782 blocks, 128-node buckets): per-bucket CSR finalize ----
__global__ __launch_bounds__(256) void build_kernel(const int* __restrict__ bbase,
                                                    const uint32* __restrict__ bbuf,
                                                    int* __restrict__ off,
                                                    float* __restrict__ dinv,
                                                    int* __restrict__ s_src) {
  __shared__ int hist[NPB];
  __shared__ int lofs[NPB];
  __shared__ int rank[NPB];
  int b = blockIdx.x, tid = threadIdx.x;
  int base = bbase[b];
  int count = bbase[b + 1] - base;
  const uint32* p = bbuf + base;
  if (tid < NPB) hist[tid] = 0;
  __syncthreads();
  for (int i = tid; i < count; i += 256) atomicAdd(&hist[p[i] >> 17], 1);
  __syncthreads();
  int deg = (tid < NPB) ? hist[tid] : 0;
  if (tid < NPB) lofs[tid] = deg;
  __syncthreads();
#pragma unroll
  for (int dd = 1; dd < NPB; dd <<= 1) {
    int t2 = (tid >= dd && tid < NPB) ? lofs[tid - dd] : 0;
    __syncthreads();
    if (tid < NPB) lofs[tid] += t2;
    __syncthreads();
  }
  int excl = (tid < NPB) ? lofs[tid] - deg : 0;
  __syncthreads();
  if (tid < NPB) {
    lofs[tid] = excl;
    rank[tid] = 0;
    int n = b * NPB + tid;
    if (n < NN) {
      off[n] = base + excl;
      dinv[n] = rsqrtf((float)deg + 1.0f);
    }
  }
  if (b == 0 && tid == 0) off[NN] = NE;
  __syncthreads();
  for (int i = tid; i < count; i += 256) {
    uint32 v = p[i];
    int dl = (int)(v >> 17);
    int s = (int)(v & 0x1FFFFu);
    int r = atomicAdd(&rank[dl], 1);
    s_src[base + lofs[dl] + r] = s;
  }
}

// ---- GEMM1 (MFMA): hs'[N,64](bf16, perm cols) = (x @ W1) * dinv[row] ----
// split-precision (xh*wh + xh*wl + xl*wh ~ fp32). 96 MFMAs/wave, no LDS.
__global__ __launch_bounds__(256) void gemm1_kernel(const float* __restrict__ x,
                                                    const uint4* __restrict__ wfrag,
                                                    const float* __restrict__ dinv,
                                                    uint32* __restrict__ hs) {
  int wid = blockIdx.x * 4 + (threadIdx.x >> 6);
  if (wid >= NN / 32) return;                 // 3125 waves exactly
  int lane = threadIdx.x & 63;
  int l15 = lane & 15, lg = lane >> 4;
  int r0 = wid * 32;
  f32x4 acc[2][4];
#pragma unroll
  for (int mr = 0; mr < 2; ++mr)
#pragma unroll
    for (int nr = 0; nr < 4; ++nr) acc[mr][nr] = (f32x4)0.f;
  const float4* x4 = (const float4*)x;
#pragma unroll
  for (int kr = 0; kr < 4; ++kr) {
    uint4 ah[2], al[2];
#pragma unroll
    for (int mr = 0; mr < 2; ++mr) {
      int m = r0 + mr * 16 + l15;
      int q0 = m * 32 + kr * 8 + lg * 2;
      float4 u = x4[q0], v = x4[q0 + 1];
      float xs[8] = {u.x, u.y, u.z, u.w, v.x, v.y, v.z, v.w};
      uint32 hw[4], lw[4];
#pragma unroll
      for (int j = 0; j < 4; ++j) {
        float a0 = xs[2 * j], a1 = xs[2 * j + 1];
        uint32 h0 = f2bf(a0), h1 = f2bf(a1);
        float ra = a0 - __uint_as_float(h0 << 16);
        float rb = a1 - __uint_as_float(h1 << 16);
        hw[j] = h0 | (h1 << 16);
        lw[j] = (uint32)f2bf(ra) | ((uint32)f2bf(rb) << 16);
      }
      ah[mr] = make_uint4(hw[0], hw[1], hw[2], hw[3]);
      al[mr] = make_uint4(lw[0], lw[1], lw[2], lw[3]);
    }
#pragma unroll
    for (int nr = 0; nr < 4; ++nr) {
      uint4 bh = wfrag[(kr * 4 + nr) * 64 + lane];
      uint4 bl = wfrag[((4 + kr) * 4 + nr) * 64 + lane];
#pragma unroll
      for (int mr = 0; mr < 2; ++mr) {
        acc[mr][nr] = mfma_bf16(ah[mr], bh, acc[mr][nr]);
        acc[mr][nr] = mfma_bf16(al[mr], bh, acc[mr][nr]);
        acc[mr][nr] = mfma_bf16(ah[mr], bl, acc[mr][nr]);
      }
    }
  }
#pragma unroll
  for (int mr = 0; mr < 2; ++mr) {
    int rb = r0 + mr * 16 + 4 * lg;
    float4 dv = *(const float4*)&dinv[rb];
#pragma unroll
    for (int a = 0; a < 2; ++a) {
#pragma unroll
      for (int j = 0; j < 4; ++j) {
        float d = (&dv.x)[j];
        uint32 wv = pack2(acc[mr][2 * a][j] * d, acc[mr][2 * a + 1][j] * d);
        hs[(size_t)(rb + j) * 32 + a * 16 + l15] = wv;
      }
    }
  }
}

// ---- agg1: wave = 8 nodes x 8 col-lanes; lane owns 8 cols of one node.
// Depth-4 gathers; no barrier. R6-proven structure. ----
__global__ __launch_bounds__(256) void agg1_kernel(const int* __restrict__ off,
                                                   const int* __restrict__ s_src,
                                                   const uint4* __restrict__ hs4,
                                                   const float* __restrict__ dinv,
                                                   const float* __restrict__ b1p,
                                                   uint4* __restrict__ g) {
  int tid = threadIdx.x;
  int n = blockIdx.x * 32 + (tid >> 3);
  int hc = tid & 7;
  int j0 = off[n], j1 = off[n + 1];
  float a[8];
  {
    uint4 v = hs4[(size_t)n * 8 + hc];    // self term
    a[0] = bf_lo(v.x); a[1] = bf_hi(v.x); a[2] = bf_lo(v.y); a[3] = bf_hi(v.y);
    a[4] = bf_lo(v.z); a[5] = bf_hi(v.z); a[6] = bf_lo(v.w); a[7] = bf_hi(v.w);
  }
  int j = j0;
  for (; j + 3 < j1; j += 4) {
    int s0 = s_src[j], s1 = s_src[j + 1], s2 = s_src[j + 2], s3 = s_src[j + 3];
    uint4 v0 = hs4[(size_t)s0 * 8 + hc];
    uint4 v1 = hs4[(size_t)s1 * 8 + hc];
    uint4 v2 = hs4[(size_t)s2 * 8 + hc];
    uint4 v3 = hs4[(size_t)s3 * 8 + hc];
    ACC8(v0); ACC8(v1); ACC8(v2); ACC8(v3);
  }
  for (; j < j1; ++j) {
    uint4 v0 = hs4[(size_t)s_src[j] * 8 + hc];
    ACC8(v0);
  }
  float di = dinv[n];
  float4 b0 = *(const float4*)&b1p[hc * 8];
  float4 b4 = *(const float4*)&b1p[hc * 8 + 4];
  float r0 = di * fmaxf(a[0] * di + b0.x, 0.f);
  float r1 = di * fmaxf(a[1] * di + b0.y, 0.f);
  float r2 = di * fmaxf(a[2] * di + b0.z, 0.f);
  float r3 = di * fmaxf(a[3] * di + b0.w, 0.f);
  float r4 = di * fmaxf(a[4] * di + b4.x, 0.f);
  float r5 = di * fmaxf(a[5] * di + b4.y, 0.f);
  float r6 = di * fmaxf(a[6] * di + b4.z, 0.f);
  float r7 = di * fmaxf(a[7] * di + b4.w, 0.f);
  uint4 o;
  o.x = pack2(r0, r1); o.y = pack2(r2, r3);
  o.z = pack2(r4, r5); o.w = pack2(r6, r7);
  g[(size_t)n * 8 + hc] = o;     // 8 lanes x 16B = 128B contiguous per node
}

// ---- gemm2: y[N,40](fp16) = g'[N,64](bf16, perm z) @ W2p (split hi/lo). ----
__global__ __launch_bounds__(256) void gemm2_kernel(const uint4* __restrict__ g4,
                                                    const uint4* __restrict__ w2frag,
                                                    unsigned short* __restrict__ y16) {
  int wid = blockIdx.x * 4 + (threadIdx.x >> 6);
  if (wid >= NN / 32) return;                 // 3125 waves
  int lane = threadIdx.x & 63;
  int l15 = lane & 15, lg = lane >> 4;
  int r0 = wid * 32;
  f32x4 acc[2][3];
#pragma unroll
  for (int mr = 0; mr < 2; ++mr)
#pragma unroll
    for (int nf = 0; nf < 3; ++nf) acc[mr][nf] = (f32x4)0.f;
#pragma unroll
  for (int kr = 0; kr < 2; ++kr) {
    uint4 a0 = g4[(size_t)(r0 + l15) * 8 + kr * 4 + lg];
    uint4 a1 = g4[(size_t)(r0 + 16 + l15) * 8 + kr * 4 + lg];
#pragma unroll
    for (int nf = 0; nf < 3; ++nf) {
      uint4 bh = w2frag[(kr * 3 + nf) * 64 + lane];          // t2=0 hi
      uint4 bl = w2frag[((2 + kr) * 3 + nf) * 64 + lane];    // t2=1 lo
      acc[0][nf] = mfma_bf16(a0, bh, acc[0][nf]);
      acc[0][nf] = mfma_bf16(a0, bl, acc[0][nf]);
      acc[1][nf] = mfma_bf16(a1, bh, acc[1][nf]);
      acc[1][nf] = mfma_bf16(a1, bl, acc[1][nf]);
    }
  }
#pragma unroll
  for (int mr = 0; mr < 2; ++mr) {
#pragma unroll
    for (int nf = 0; nf < 3; ++nf) {
      int col = nf * 16 + l15;
      if (col < NCLS) {
#pragma unroll
        for (int j = 0; j < 4; ++j) {
          int row = r0 + mr * 16 + 4 * lg + j;
          __half h = __float2half(acc[mr][nf][j]);
          y16[(size_t)row * NCLS + col] = __builtin_bit_cast(unsigned short, h);
        }
      }
    }
  }
}

// ---- agg2y: out[n] = dinv_n*(y[n] + sum_src y[src]) + b2. 5 lanes/node. ----
__global__ __launch_bounds__(256) void agg2y_kernel(const int* __restrict__ off,
                                                    const int* __restrict__ s_src,
                                                    const uint4* __restrict__ y4,
                                                    const float* __restrict__ dinv,
                                                    const float* __restrict__ b2,
                                                    float* __restrict__ out) {
  int T = blockIdx.x * 256 + threadIdx.x;
  int n = T / 5;
  int sub = T - n * 5;            // 16B chunk (8 of 40 fp16 cols)
  if (n >= NN) return;
  int j0 = off[n], j1 = off[n + 1];
  float a[8];
  {
    uint4 v = y4[(size_t)n * 5 + sub];   // self term
    float2 f0 = h2f2(v.x), f1 = h2f2(v.y), f2 = h2f2(v.z), f3 = h2f2(v.w);
    a[0] = f0.x; a[1] = f0.y; a[2] = f1.x; a[3] = f1.y;
    a[4] = f2.x; a[5] = f2.y; a[6] = f3.x; a[7] = f3.y;
  }
  int j = j0;
  for (; j + 3 < j1; j += 4) {
    int s0 = s_src[j], s1 = s_src[j + 1], s2 = s_src[j + 2], s3 = s_src[j + 3];
    uint4 v0 = y4[(size_t)s0 * 5 + sub];
    uint4 v1 = y4[(size_t)s1 * 5 + sub];
    uint4 v2 = y4[(size_t)s2 * 5 + sub];
    uint4 v3 = y4[(size_t)s3 * 5 + sub];
    ACC8H(v0); ACC8H(v1); ACC8H(v2); ACC8H(v3);
  }
  for (; j < j1; ++j) {
    uint4 v0 = y4[(size_t)s_src[j] * 5 + sub];
    ACC8H(v0);
  }
  float di = dinv[n];
  int c0 = sub * 8;
  float4 bb0 = *(const float4*)&b2[c0];
  float4 bb1 = *(const float4*)&b2[c0 + 4];
  float* op = &out[(size_t)n * NCLS + c0];
  *(float4*)op = make_float4(a[0] * di + bb0.x, a[1] * di + bb0.y,
                             a[2] * di + bb0.z, a[3] * di + bb0.w);
  *(float4*)(op + 4) = make_float4(a[4] * di + bb1.x, a[5] * di + bb1.y,
                                   a[6] * di + bb1.z, a[7] * di + bb1.w);
}

extern "C" void kernel_launch(void* const* d_in, const int* in_sizes, int n_in,
                              void* d_out, int out_size, void* d_ws, size_t ws_size,
                              hipStream_t stream) {
  const float* x  = (const float*)d_in[0];
  const void*  ei = d_in[1];
  const float* W1 = (const float*)d_in[2];
  const float* b1 = (const float*)d_in[3];
  const float* W2 = (const float*)d_in[4];
  const float* b2 = (const float*)d_in[5];
  float* out = (float*)d_out;

  char* w = (char*)d_ws;
  size_t off_b = 0;
  auto carve = [&](size_t bytes) -> void* {
    void* p = w + off_b;
    off_b = (off_b + bytes + 255) & ~(size_t)255;
    return p;
  };
  int*    mat    = (int*)   carve((size_t)NEB * NBUCK * 4);   // 2.45 MB
  int*    tot    = (int*)   carve((size_t)NBUCK * 4);
  int*    bbase  = (int*)   carve((size_t)(NBUCK + 1) * 4);
  int*    offs   = (int*)   carve((size_t)(NN + 1) * 4);
  float*  dinv   = (float*) carve((size_t)NN * 4);
  int*    flag   = (int*)   carve(256);
  int*    s_src  = (int*)   carve((size_t)NE * 4);
  uint32* hs     = (uint32*)carve((size_t)NN * 32 * 4);       // bf16 h, 12.8 MB
  uint4*  g      = (uint4*) carve((size_t)NN * 8 * 16);       // bf16 g, 12.8 MB
  uint32* bbuf   = (uint32*)carve((size_t)NE * 4);            // 6.4 MB
  uint4*  wfrag  = (uint4*) carve((size_t)2048 * 16);         // 32 KB
  uint4*  w2frag = (uint4*) carve((size_t)768 * 16);          // 12 KB
  float*  b1p    = (float*) carve((size_t)HIDN * 4);          // 256 B
  unsigned short* y16 = (unsigned short*)carve((size_t)NN * NCLS * 2);  // 8 MB

  wfrag_kernel<<<45, 64, 0, stream>>>(W1, b1, W2, (const unsigned int*)ei,
                                      wfrag, w2frag, b1p, flag);
  passA_kernel<<<NEB, 256, 0, stream>>>(ei, flag, mat);
  passB1_kernel<<<NBUCK, 1024, 0, stream>>>(mat, tot);
  passB2_kernel<<<1, 1024, 0, stream>>>(tot, bbase);
  passC_kernel<<<NEB, 256, 0, stream>>>(ei, flag, mat, bbase, bbuf);
  build_kernel<<<NBUCK, 256, 0, stream>>>(bbase, bbuf, offs, dinv, s_src);
  gemm1_kernel<<<(NN / 32 + 3) / 4, 256, 0, stream>>>(x, wfrag, dinv, hs);
  agg1_kernel<<<NN / 32, 256, 0, stream>>>(offs, s_src, (const uint4*)hs, dinv, b1p, g);
  gemm2_kernel<<<(NN / 32 + 3) / 4, 256, 0, stream>>>(g, w2frag, y16);
  agg2y_kernel<<<(NN * 5 + 255) / 256, 256, 0, stream>>>(offs, s_src,
                                                         (const uint4*)y16, dinv, b2, out);
}

// Round 12
// 231.139 us; speedup vs baseline: 1.0301x; 1.0301x over previous
//
#include <hip/hip_runtime.h>
#include <hip/hip_fp16.h>
#include <stdint.h>

#define NN    100000
#define FIN   128
#define HIDN  64
#define NCLS  40
#define NE    1600000
#define NBUCK ((NN + 255) / 256)      // 391 buckets of 256 nodes (R10-proven)
#define EPB   2048                    // edges per partition block (R12: halved)
#define NEB   ((NE + EPB - 1) / EPB)  // 782 partition blocks = 3/CU

typedef unsigned int uint32;
typedef __attribute__((ext_vector_type(8))) short short8v;
typedef __attribute__((ext_vector_type(4))) float f32x4;

static __device__ __forceinline__ unsigned short f2bf(float f) {
  uint32 u = __float_as_uint(f);
  u = (u + 0x7fffu + ((u >> 16) & 1u)) >> 16;   // RNE
  return (unsigned short)u;
}
static __device__ __forceinline__ uint32 pack2(float lo, float hi) {
  return (uint32)f2bf(lo) | ((uint32)f2bf(hi) << 16);
}
static __device__ __forceinline__ float bf_lo(uint32 v) {
  return __uint_as_float(v << 16);
}
static __device__ __forceinline__ float bf_hi(uint32 v) {
  return __uint_as_float(v & 0xFFFF0000u);
}
static __device__ __forceinline__ float2 h2f2(uint32 w) {
  __half2 h = __builtin_bit_cast(__half2, w);
  return __half22float2(h);
}
static __device__ __forceinline__ f32x4 mfma_bf16(uint4 a, uint4 b, f32x4 c) {
  short8v av = __builtin_bit_cast(short8v, a);
  short8v bv = __builtin_bit_cast(short8v, b);
  return __builtin_amdgcn_mfma_f32_16x16x32_bf16(av, bv, c, 0, 0, 0);
}

// permuted hs/g column map: float index z in [0,64) -> true column.
static __device__ __forceinline__ int perm_col(int z) {
  return 4 * (z >> 3) + ((z & 7) >> 1) + 16 * (z & 1) + ((z >= 32) ? 16 : 0);
}

// accumulate 8 bf16 lanes of a uint4 into a[8]
#define ACC8(v)                                                              \
  do {                                                                       \
    a[0] += bf_lo((v).x); a[1] += bf_hi((v).x);                              \
    a[2] += bf_lo((v).y); a[3] += bf_hi((v).y);                              \
    a[4] += bf_lo((v).z); a[5] += bf_hi((v).z);                              \
    a[6] += bf_lo((v).w); a[7] += bf_hi((v).w);                              \
  } while (0)

// accumulate 8 fp16 lanes of a uint4 into a[8]
#define ACC8H(v)                                                             \
  do {                                                                       \
    float2 f0 = h2f2((v).x), f1 = h2f2((v).y);                               \
    float2 f2 = h2f2((v).z), f3 = h2f2((v).w);                               \
    a[0] += f0.x; a[1] += f0.y; a[2] += f1.x; a[3] += f1.y;                  \
    a[4] += f2.x; a[5] += f2.y; a[6] += f3.x; a[7] += f3.y;                  \
  } while (0)

// ---- wfrag+probe (merged): W1 frags (blocks 0..31), W2 frags split hi/lo
// (blocks 32..43), probe+b1p (block 44). ----
__global__ __launch_bounds__(64) void wfrag_kernel(const float* __restrict__ W,
                                                   const float* __restrict__ b1,
                                                   const float* __restrict__ W2,
                                                   const unsigned int* __restrict__ raw,
                                                   uint4* __restrict__ wfrag,
                                                   uint4* __restrict__ w2frag,
                                                   float* __restrict__ b1p,
                                                   int* __restrict__ flag) {
  int bk = blockIdx.x;
  int tid = threadIdx.x;
  if (bk < 32) {
    // W1[128][64] -> MFMA B-frag order, split hi/lo bf16.
    // frag idx = ((t*4 + kr)*4 + nr)*64 + lane
    int idx = bk * 64 + tid;
    int lane = idx & 63;
    int nr = (idx >> 6) & 3;
    int kr = (idx >> 8) & 3;
    int t  = idx >> 10;                        // 0 = hi, 1 = lo
    int n  = nr * 16 + (lane & 15);
    int k0 = kr * 32 + (lane >> 4) * 8;
    uint32 w[4];
#pragma unroll
    for (int j = 0; j < 4; ++j) {
      float a = W[(k0 + 2 * j) * HIDN + n];
      float b = W[(k0 + 2 * j + 1) * HIDN + n];
      uint32 ha = f2bf(a), hb = f2bf(b);
      if (t == 0) {
        w[j] = ha | (hb << 16);
      } else {
        float ra = a - __uint_as_float(ha << 16);
        float rb = b - __uint_as_float(hb << 16);
        w[j] = (uint32)f2bf(ra) | ((uint32)f2bf(rb) << 16);
      }
    }
    wfrag[idx] = make_uint4(w[0], w[1], w[2], w[3]);
  } else if (bk < 44) {
    // W2p[z][c] = W2[perm_col(z)][c] -> B-frags for gemm2 (K=64, N=48 pad).
    int f = bk - 32;                 // 0..11 = t2*6 + kr*3 + nf
    int t2 = f / 6;
    int kr = (f / 3) % 2;
    int nf = f % 3;
    int c  = nf * 16 + (tid & 15);
    int k0 = kr * 32 + (tid >> 4) * 8;
    uint32 w[4];
#pragma unroll
    for (int j = 0; j < 4; ++j) {
      float a = (c < NCLS) ? W2[perm_col(k0 + 2 * j) * NCLS + c] : 0.f;
      float b = (c < NCLS) ? W2[perm_col(k0 + 2 * j + 1) * NCLS + c] : 0.f;
      uint32 ha = f2bf(a), hb = f2bf(b);
      if (t2 == 0) {
        w[j] = ha | (hb << 16);
      } else {
        float ra = a - __uint_as_float(ha << 16);
        float rb = b - __uint_as_float(hb << 16);
        w[j] = (uint32)f2bf(ra) | ((uint32)f2bf(rb) << 16);
      }
    }
    w2frag[f * 64 + tid] = make_uint4(w[0], w[1], w[2], w[3]);
  } else {
    b1p[tid] = b1[perm_col(tid)];
    if (tid == 0) {
      int is64 = 1;
      for (int i = 0; i < 64; ++i)
        if (raw[2 * i + 1] != 0u) { is64 = 0; break; }
      *flag = is64;
    }
  }
}

// ---- passA (R12: EPB 2048 -> 782 blocks = 3/CU; buckets unchanged) ----
__global__ __launch_bounds__(256) void passA_kernel(const void* __restrict__ eptr,
                                                    const int* __restrict__ flag,
                                                    int* __restrict__ mat) {
  __shared__ int cnt[NBUCK];
  int tid = threadIdx.x;
  for (int i = tid; i < NBUCK; i += 256) cnt[i] = 0;
  __syncthreads();
  int is64 = *flag;
  int base = blockIdx.x * EPB;
#pragma unroll
  for (int k = 0; k < EPB / 256; ++k) {
    int e = base + k * 256 + tid;
    if (e < NE) {
      int d = is64 ? (int)((const long long*)eptr)[e + NE]
                   : ((const int*)eptr)[e + NE];
      atomicAdd(&cnt[d >> 8], 1);
    }
  }
  __syncthreads();
  for (int i = tid; i < NBUCK; i += 256)
    mat[blockIdx.x * NBUCK + i] = cnt[i];
}

// ---- passB1 (R12: 1024-thr scan over NEB=782 blocks; 391 bucket-blocks) ----
__global__ __launch_bounds__(1024) void passB1_kernel(int* __restrict__ mat,
                                                      int* __restrict__ tot) {
  __shared__ int s[1024];
  int b = blockIdx.x;         // bucket
  int t = threadIdx.x;        // block index
  int v = (t < NEB) ? mat[t * NBUCK + b] : 0;
  s[t] = v;
  __syncthreads();
#pragma unroll
  for (int d = 1; d < 1024; d <<= 1) {
    int u = (t >= d) ? s[t - d] : 0;
    __syncthreads();
    s[t] += u;
    __syncthreads();
  }
  if (t < NEB) mat[t * NBUCK + b] = s[t] - v;  // exclusive prefix within bucket
  if (t == 1023) tot[b] = s[1023];
}

// ---- passB2: exclusive scan of bucket totals -> bbase (R10 form) ----
__global__ __launch_bounds__(512) void passB2_kernel(const int* __restrict__ tot,
                                                     int* __restrict__ bbase) {
  __shared__ int s[512];
  int i = threadIdx.x;
  int v = (i < NBUCK) ? tot[i] : 0;
  s[i] = v;
  __syncthreads();
#pragma unroll
  for (int d = 1; d < 512; d <<= 1) {
    int u = (i >= d) ? s[i - d] : 0;
    __syncthreads();
    s[i] += u;
    __syncthreads();
  }
  if (i < NBUCK) bbase[i] = s[i] - v;
  if (i == 511) bbase[NBUCK] = s[511];
}

// ---- passC (R12: 782 blocks; bucket encoding unchanged from R10) ----
__global__ __launch_bounds__(256) void passC_kernel(const void* __restrict__ eptr,
                                                    const int* __restrict__ flag,
                                                    const int* __restrict__ mat,
                                                    const int* __restrict__ bbase,
                                                    uint32* __restrict__ bbuf) {
  __shared__ int cur[NBUCK];
  int tid = threadIdx.x;
  for (int i = tid; i < NBUCK; i += 256)
    cur[i] = bbase[i] + mat[blockIdx.x * NBUCK + i];
  __syncthreads();
  int is64 = *flag;
  int base = blockIdx.x * EPB;
#pragma unroll
  for (int k = 0; k < EPB / 256; ++k) {
    int e = base + k * 256 + tid;
    if (e < NE) {
      int s, d;
      if (is64) {
        const long long* p = (const long long*)eptr;
        s = (int)p[e]; d = (int)p[e + NE];
      } else {
        const int* p = (const int*)eptr;
        s = p[e]; d = p[e + NE];
      }
      int slot = atomicAdd(&cur[d >> 8], 1);
      bbuf[slot] = (uint32)s | ((uint32)(d & 255) << 17);
    }
  }
}

// ---- build: per-bucket CSR (R10 form, 256-node buckets) ----
__global__ __launch_bounds__(256) void build_kernel(const int* __restrict__ bbase,
                                                    const uint32* __restrict__ bbuf,
                                                    int* __restrict__ off,
                                                    float* __restrict__ dinv,
                                                    int* __restrict__ s_src) {
  __shared__ int hist[256];
  __shared__ int lofs[256];
  __shared__ int rank[256];
  int b = blockIdx.x, tid = threadIdx.x;
  int base = bbase[b];
  int count = bbase[b + 1] - base;
  const uint32* p = bbuf + base;
  hist[tid] = 0;
  __syncthreads();
  for (int i = tid; i < count; i += 256) atomicAdd(&hist[p[i] >> 17], 1);
  __syncthreads();
  int deg = hist[tid];
  lofs[tid] = deg;
  __syncthreads();
#pragma unroll
  for (int dd = 1; dd < 256; dd <<= 1) {
    int t = (tid >= dd) ? lofs[tid - dd] : 0;
    __syncthreads();
    lofs[tid] += t;
    __syncthreads();
  }
  int excl = lofs[tid] - deg;
  __syncthreads();
  lofs[tid] = excl;
  rank[tid] = 0;
  int n = b * 256 + tid;
  if (n < NN) {
    off[n] = base + excl;
    dinv[n] = rsqrtf((float)deg + 1.0f);
  }
  if (b == 0 && tid == 0) off[NN] = NE;
  __syncthreads();
  for (int i = tid; i < count; i += 256) {
    uint32 v = p[i];
    int dl = (int)(v >> 17);
    int s = (int)(v & 0x1FFFFu);
    int r = atomicAdd(&rank[dl], 1);
    s_src[base + lofs[dl] + r] = s;
  }
}

// ---- GEMM1 (MFMA): hs'[N,64](bf16, perm cols) = (x @ W1) * dinv[row] ----
// split-precision (xh*wh + xh*wl + xl*wh ~ fp32). 96 MFMAs/wave, no LDS.
__global__ __launch_bounds__(256) void gemm1_kernel(const float* __restrict__ x,
                                                    const uint4* __restrict__ wfrag,
                                                    const float* __restrict__ dinv,
                                                    uint32* __restrict__ hs) {
  int wid = blockIdx.x * 4 + (threadIdx.x >> 6);
  if (wid >= NN / 32) return;                 // 3125 waves exactly
  int lane = threadIdx.x & 63;
  int l15 = lane & 15, lg = lane >> 4;
  int r0 = wid * 32;
  f32x4 acc[2][4];
#pragma unroll
  for (int mr = 0; mr < 2; ++mr)
#pragma unroll
    for (int nr = 0; nr < 4; ++nr) acc[mr][nr] = (f32x4)0.f;
  const float4* x4 = (const float4*)x;
#pragma unroll
  for (int kr = 0; kr < 4; ++kr) {
    uint4 ah[2], al[2];
#pragma unroll
    for (int mr = 0; mr < 2; ++mr) {
      int m = r0 + mr * 16 + l15;
      int q0 = m * 32 + kr * 8 + lg * 2;
      float4 u = x4[q0], v = x4[q0 + 1];
      float xs[8] = {u.x, u.y, u.z, u.w, v.x, v.y, v.z, v.w};
      uint32 hw[4], lw[4];
#pragma unroll
      for (int j = 0; j < 4; ++j) {
        float a0 = xs[2 * j], a1 = xs[2 * j + 1];
        uint32 h0 = f2bf(a0), h1 = f2bf(a1);
        float ra = a0 - __uint_as_float(h0 << 16);
        float rb = a1 - __uint_as_float(h1 << 16);
        hw[j] = h0 | (h1 << 16);
        lw[j] = (uint32)f2bf(ra) | ((uint32)f2bf(rb) << 16);
      }
      ah[mr] = make_uint4(hw[0], hw[1], hw[2], hw[3]);
      al[mr] = make_uint4(lw[0], lw[1], lw[2], lw[3]);
    }
#pragma unroll
    for (int nr = 0; nr < 4; ++nr) {
      uint4 bh = wfrag[(kr * 4 + nr) * 64 + lane];
      uint4 bl = wfrag[((4 + kr) * 4 + nr) * 64 + lane];
#pragma unroll
      for (int mr = 0; mr < 2; ++mr) {
        acc[mr][nr] = mfma_bf16(ah[mr], bh, acc[mr][nr]);
        acc[mr][nr] = mfma_bf16(al[mr], bh, acc[mr][nr]);
        acc[mr][nr] = mfma_bf16(ah[mr], bl, acc[mr][nr]);
      }
    }
  }
#pragma unroll
  for (int mr = 0; mr < 2; ++mr) {
    int rb = r0 + mr * 16 + 4 * lg;
    float4 dv = *(const float4*)&dinv[rb];
#pragma unroll
    for (int a = 0; a < 2; ++a) {
#pragma unroll
      for (int j = 0; j < 4; ++j) {
        float d = (&dv.x)[j];
        uint32 wv = pack2(acc[mr][2 * a][j] * d, acc[mr][2 * a + 1][j] * d);
        hs[(size_t)(rb + j) * 32 + a * 16 + l15] = wv;
      }
    }
  }
}

// ---- agg1: wave = 8 nodes x 8 col-lanes; lane owns 8 cols of one node.
// Depth-4 gathers; no barrier. R6-proven structure. ----
__global__ __launch_bounds__(256) void agg1_kernel(const int* __restrict__ off,
                                                   const int* __restrict__ s_src,
                                                   const uint4* __restrict__ hs4,
                                                   const float* __restrict__ dinv,
                                                   const float* __restrict__ b1p,
                                                   uint4* __restrict__ g) {
  int tid = threadIdx.x;
  int n = blockIdx.x * 32 + (tid >> 3);
  int hc = tid & 7;
  int j0 = off[n], j1 = off[n + 1];
  float a[8];
  {
    uint4 v = hs4[(size_t)n * 8 + hc];    // self term
    a[0] = bf_lo(v.x); a[1] = bf_hi(v.x); a[2] = bf_lo(v.y); a[3] = bf_hi(v.y);
    a[4] = bf_lo(v.z); a[5] = bf_hi(v.z); a[6] = bf_lo(v.w); a[7] = bf_hi(v.w);
  }
  int j = j0;
  for (; j + 3 < j1; j += 4) {
    int s0 = s_src[j], s1 = s_src[j + 1], s2 = s_src[j + 2], s3 = s_src[j + 3];
    uint4 v0 = hs4[(size_t)s0 * 8 + hc];
    uint4 v1 = hs4[(size_t)s1 * 8 + hc];
    uint4 v2 = hs4[(size_t)s2 * 8 + hc];
    uint4 v3 = hs4[(size_t)s3 * 8 + hc];
    ACC8(v0); ACC8(v1); ACC8(v2); ACC8(v3);
  }
  for (; j < j1; ++j) {
    uint4 v0 = hs4[(size_t)s_src[j] * 8 + hc];
    ACC8(v0);
  }
  float di = dinv[n];
  float4 b0 = *(const float4*)&b1p[hc * 8];
  float4 b4 = *(const float4*)&b1p[hc * 8 + 4];
  float r0 = di * fmaxf(a[0] * di + b0.x, 0.f);
  float r1 = di * fmaxf(a[1] * di + b0.y, 0.f);
  float r2 = di * fmaxf(a[2] * di + b0.z, 0.f);
  float r3 = di * fmaxf(a[3] * di + b0.w, 0.f);
  float r4 = di * fmaxf(a[4] * di + b4.x, 0.f);
  float r5 = di * fmaxf(a[5] * di + b4.y, 0.f);
  float r6 = di * fmaxf(a[6] * di + b4.z, 0.f);
  float r7 = di * fmaxf(a[7] * di + b4.w, 0.f);
  uint4 o;
  o.x = pack2(r0, r1); o.y = pack2(r2, r3);
  o.z = pack2(r4, r5); o.w = pack2(r6, r7);
  g[(size_t)n * 8 + hc] = o;     // 8 lanes x 16B = 128B contiguous per node
}

// ---- gemm2: y[N,40](fp16) = g'[N,64](bf16, perm z) @ W2p (split hi/lo). ----
__global__ __launch_bounds__(256) void gemm2_kernel(const uint4* __restrict__ g4,
                                                    const uint4* __restrict__ w2frag,
                                                    unsigned short* __restrict__ y16) {
  int wid = blockIdx.x * 4 + (threadIdx.x >> 6);
  if (wid >= NN / 32) return;                 // 3125 waves
  int lane = threadIdx.x & 63;
  int l15 = lane & 15, lg = lane >> 4;
  int r0 = wid * 32;
  f32x4 acc[2][3];
#pragma unroll
  for (int mr = 0; mr < 2; ++mr)
#pragma unroll
    for (int nf = 0; nf < 3; ++nf) acc[mr][nf] = (f32x4)0.f;
#pragma unroll
  for (int kr = 0; kr < 2; ++kr) {
    uint4 a0 = g4[(size_t)(r0 + l15) * 8 + kr * 4 + lg];
    uint4 a1 = g4[(size_t)(r0 + 16 + l15) * 8 + kr * 4 + lg];
#pragma unroll
    for (int nf = 0; nf < 3; ++nf) {
      uint4 bh = w2frag[(kr * 3 + nf) * 64 + lane];          // t2=0 hi
      uint4 bl = w2frag[((2 + kr) * 3 + nf) * 64 + lane];    // t2=1 lo
      acc[0][nf] = mfma_bf16(a0, bh, acc[0][nf]);
      acc[0][nf] = mfma_bf16(a0, bl, acc[0][nf]);
      acc[1][nf] = mfma_bf16(a1, bh, acc[1][nf]);
      acc[1][nf] = mfma_bf16(a1, bl, acc[1][nf]);
    }
  }
#pragma unroll
  for (int mr = 0; mr < 2; ++mr) {
#pragma unroll
    for (int nf = 0; nf < 3; ++nf) {
      int col = nf * 16 + l15;
      if (col < NCLS) {
#pragma unroll
        for (int j = 0; j < 4; ++j) {
          int row = r0 + mr * 16 + 4 * lg + j;
          __half h = __float2half(acc[mr][nf][j]);
          y16[(size_t)row * NCLS + col] = __builtin_bit_cast(unsigned short, h);
        }
      }
    }
  }
}

// ---- agg2y: out[n] = dinv_n*(y[n] + sum_src y[src]) + b2. 5 lanes/node. ----
__global__ __launch_bounds__(256) void agg2y_kernel(const int* __restrict__ off,
                                                    const int* __restrict__ s_src,
                                                    const uint4* __restrict__ y4,
                                                    const float* __restrict__ dinv,
                                                    const float* __restrict__ b2,
                                                    float* __restrict__ out) {
  int T = blockIdx.x * 256 + threadIdx.x;
  int n = T / 5;
  int sub = T - n * 5;            // 16B chunk (8 of 40 fp16 cols)
  if (n >= NN) return;
  int j0 = off[n], j1 = off[n + 1];
  float a[8];
  {
    uint4 v = y4[(size_t)n * 5 + sub];   // self term
    float2 f0 = h2f2(v.x), f1 = h2f2(v.y), f2 = h2f2(v.z), f3 = h2f2(v.w);
    a[0] = f0.x; a[1] = f0.y; a[2] = f1.x; a[3] = f1.y;
    a[4] = f2.x; a[5] = f2.y; a[6] = f3.x; a[7] = f3.y;
  }
  int j = j0;
  for (; j + 3 < j1; j += 4) {
    int s0 = s_src[j], s1 = s_src[j + 1], s2 = s_src[j + 2], s3 = s_src[j + 3];
    uint4 v0 = y4[(size_t)s0 * 5 + sub];
    uint4 v1 = y4[(size_t)s1 * 5 + sub];
    uint4 v2 = y4[(size_t)s2 * 5 + sub];
    uint4 v3 = y4[(size_t)s3 * 5 + sub];
    ACC8H(v0); ACC8H(v1); ACC8H(v2); ACC8H(v3);
  }
  for (; j < j1; ++j) {
    uint4 v0 = y4[(size_t)s_src[j] * 5 + sub];
    ACC8H(v0);
  }
  float di = dinv[n];
  int c0 = sub * 8;
  float4 bb0 = *(const float4*)&b2[c0];
  float4 bb1 = *(const float4*)&b2[c0 + 4];
  float* op = &out[(size_t)n * NCLS + c0];
  *(float4*)op = make_float4(a[0] * di + bb0.x, a[1] * di + bb0.y,
                             a[2] * di + bb0.z, a[3] * di + bb0.w);
  *(float4*)(op + 4) = make_float4(a[4] * di + bb1.x, a[5] * di + bb1.y,
                                   a[6] * di + bb1.z, a[7] * di + bb1.w);
}

extern "C" void kernel_launch(void* const* d_in, const int* in_sizes, int n_in,
                              void* d_out, int out_size, void* d_ws, size_t ws_size,
                              hipStream_t stream) {
  const float* x  = (const float*)d_in[0];
  const void*  ei = d_in[1];
  const float* W1 = (const float*)d_in[2];
  const float* b1 = (const float*)d_in[3];
  const float* W2 = (const float*)d_in[4];
  const float* b2 = (const float*)d_in[5];
  float* out = (float*)d_out;

  char* w = (char*)d_ws;
  size_t off_b = 0;
  auto carve = [&](size_t bytes) -> void* {
    void* p = w + off_b;
    off_b = (off_b + bytes + 255) & ~(size_t)255;
    return p;
  };
  int*    mat    = (int*)   carve((size_t)NEB * NBUCK * 4);   // 1.22 MB
  int*    tot    = (int*)   carve((size_t)NBUCK * 4);
  int*    bbase  = (int*)   carve((size_t)(NBUCK + 1) * 4);
  int*    offs   = (int*)   carve((size_t)(NN + 1) * 4);
  float*  dinv   = (float*) carve((size_t)NN * 4);
  int*    flag   = (int*)   carve(256);
  int*    s_src  = (int*)   carve((size_t)NE * 4);
  uint32* hs     = (uint32*)carve((size_t)NN * 32 * 4);       // bf16 h, 12.8 MB
  uint4*  g      = (uint4*) carve((size_t)NN * 8 * 16);       // bf16 g, 12.8 MB
  uint32* bbuf   = (uint32*)carve((size_t)NE * 4);            // 6.4 MB
  uint4*  wfrag  = (uint4*) carve((size_t)2048 * 16);         // 32 KB
  uint4*  w2frag = (uint4*) carve((size_t)768 * 16);          // 12 KB
  float*  b1p    = (float*) carve((size_t)HIDN * 4);          // 256 B
  unsigned short* y16 = (unsigned short*)carve((size_t)NN * NCLS * 2);  // 8 MB

  wfrag_kernel<<<45, 64, 0, stream>>>(W1, b1, W2, (const unsigned int*)ei,
                                      wfrag, w2frag, b1p, flag);
  passA_kernel<<<NEB, 256, 0, stream>>>(ei, flag, mat);
  passB1_kernel<<<NBUCK, 1024, 0, stream>>>(mat, tot);
  passB2_kernel<<<1, 512, 0, stream>>>(tot, bbase);
  passC_kernel<<<NEB, 256, 0, stream>>>(ei, flag, mat, bbase, bbuf);
  build_kernel<<<NBUCK, 256, 0, stream>>>(bbase, bbuf, offs, dinv, s_src);
  gemm1_kernel<<<(NN / 32 + 3) / 4, 256, 0, stream>>>(x, wfrag, dinv, hs);
  agg1_kernel<<<NN / 32, 256, 0, stream>>>(offs, s_src, (const uint4*)hs, dinv, b1p, g);
  gemm2_kernel<<<(NN / 32 + 3) / 4, 256, 0, stream>>>(g, w2frag, y16);
  agg2y_kernel<<<(NN * 5 + 255) / 256, 256, 0, stream>>>(offs, s_src,
                                                         (const uint4*)y16, dinv, b2, out);
}

// Round 13
// 221.976 us; speedup vs baseline: 1.0726x; 1.0413x over previous
//
#include <hip/hip_runtime.h>
#include <hip/hip_fp16.h>
#include <stdint.h>

#define NN    100000
#define FIN   128
#define HIDN  64
#define NCLS  40
#define NE    1600000
#define NBUCK ((NN + 255) / 256)      // 391 buckets of 256 nodes (R10-proven)
#define EPB   4096                    // edges per partition block (R10-proven)
#define NEB   ((NE + EPB - 1) / EPB)  // 391 partition blocks
#define NWF   45                      // wfrag blocks prepended to passA grid

typedef unsigned int uint32;
typedef __attribute__((ext_vector_type(8))) short short8v;
typedef __attribute__((ext_vector_type(4))) float f32x4;

static __device__ __forceinline__ unsigned short f2bf(float f) {
  uint32 u = __float_as_uint(f);
  u = (u + 0x7fffu + ((u >> 16) & 1u)) >> 16;   // RNE
  return (unsigned short)u;
}
static __device__ __forceinline__ uint32 pack2(float lo, float hi) {
  return (uint32)f2bf(lo) | ((uint32)f2bf(hi) << 16);
}
static __device__ __forceinline__ float bf_lo(uint32 v) {
  return __uint_as_float(v << 16);
}
static __device__ __forceinline__ float bf_hi(uint32 v) {
  return __uint_as_float(v & 0xFFFF0000u);
}
static __device__ __forceinline__ float2 h2f2(uint32 w) {
  __half2 h = __builtin_bit_cast(__half2, w);
  return __half22float2(h);
}
static __device__ __forceinline__ f32x4 mfma_bf16(uint4 a, uint4 b, f32x4 c) {
  short8v av = __builtin_bit_cast(short8v, a);
  short8v bv = __builtin_bit_cast(short8v, b);
  return __builtin_amdgcn_mfma_f32_16x16x32_bf16(av, bv, c, 0, 0, 0);
}

// permuted hs/g column map: float index z in [0,64) -> true column.
static __device__ __forceinline__ int perm_col(int z) {
  return 4 * (z >> 3) + ((z & 7) >> 1) + 16 * (z & 1) + ((z >= 32) ? 16 : 0);
}

// accumulate 8 bf16 lanes of a uint4 into a[8]
#define ACC8(v)                                                              \
  do {                                                                       \
    a[0] += bf_lo((v).x); a[1] += bf_hi((v).x);                              \
    a[2] += bf_lo((v).y); a[3] += bf_hi((v).y);                              \
    a[4] += bf_lo((v).z); a[5] += bf_hi((v).z);                              \
    a[6] += bf_lo((v).w); a[7] += bf_hi((v).w);                              \
  } while (0)

// accumulate 8 fp16 lanes of a uint4 into a[8]
#define ACC8H(v)                                                             \
  do {                                                                       \
    float2 f0 = h2f2((v).x), f1 = h2f2((v).y);                               \
    float2 f2 = h2f2((v).z), f3 = h2f2((v).w);                               \
    a[0] += f0.x; a[1] += f0.y; a[2] += f1.x; a[3] += f1.y;                  \
    a[4] += f2.x; a[5] += f2.y; a[6] += f3.x; a[7] += f3.y;                  \
  } while (0)

// ---- passAW (R13 merge): blocks 0..44 = wfrag/W2frag/b1p/flag prep (tid<64),
// blocks 45.. = passA bucket histogram with INLINE is64 ballot probe (each
// wave reads the same 64 high-words -> identical per-wave verdict; no LDS,
// no barrier, no same-kernel flag dependency). flag still written (block 44)
// for passC, which launches later. ----
__global__ __launch_bounds__(256) void passAW_kernel(const float* __restrict__ W,
                                                     const float* __restrict__ b1,
                                                     const float* __restrict__ W2,
                                                     const void* __restrict__ eptr,
                                                     uint4* __restrict__ wfrag,
                                                     uint4* __restrict__ w2frag,
                                                     float* __restrict__ b1p,
                                                     int* __restrict__ flag,
                                                     int* __restrict__ mat) {
  int bk = blockIdx.x;
  int tid = threadIdx.x;
  if (bk < NWF) {
    if (tid >= 64) return;
    if (bk < 32) {
      // W1[128][64] -> MFMA B-frag order, split hi/lo bf16.
      int idx = bk * 64 + tid;
      int lane = idx & 63;
      int nr = (idx >> 6) & 3;
      int kr = (idx >> 8) & 3;
      int t  = idx >> 10;                        // 0 = hi, 1 = lo
      int n  = nr * 16 + (lane & 15);
      int k0 = kr * 32 + (lane >> 4) * 8;
      uint32 w[4];
#pragma unroll
      for (int j = 0; j < 4; ++j) {
        float a = W[(k0 + 2 * j) * HIDN + n];
        float b = W[(k0 + 2 * j + 1) * HIDN + n];
        uint32 ha = f2bf(a), hb = f2bf(b);
        if (t == 0) {
          w[j] = ha | (hb << 16);
        } else {
          float ra = a - __uint_as_float(ha << 16);
          float rb = b - __uint_as_float(hb << 16);
          w[j] = (uint32)f2bf(ra) | ((uint32)f2bf(rb) << 16);
        }
      }
      wfrag[idx] = make_uint4(w[0], w[1], w[2], w[3]);
    } else if (bk < 44) {
      // W2p[z][c] = W2[perm_col(z)][c] -> B-frags for gemm2 (K=64, N=48 pad).
      int f = bk - 32;                 // 0..11 = t2*6 + kr*3 + nf
      int t2 = f / 6;
      int kr = (f / 3) % 2;
      int nf = f % 3;
      int c  = nf * 16 + (tid & 15);
      int k0 = kr * 32 + (tid >> 4) * 8;
      uint32 w[4];
#pragma unroll
      for (int j = 0; j < 4; ++j) {
        float a = (c < NCLS) ? W2[perm_col(k0 + 2 * j) * NCLS + c] : 0.f;
        float b = (c < NCLS) ? W2[perm_col(k0 + 2 * j + 1) * NCLS + c] : 0.f;
        uint32 ha = f2bf(a), hb = f2bf(b);
        if (t2 == 0) {
          w[j] = ha | (hb << 16);
        } else {
          float ra = a - __uint_as_float(ha << 16);
          float rb = b - __uint_as_float(hb << 16);
          w[j] = (uint32)f2bf(ra) | ((uint32)f2bf(rb) << 16);
        }
      }
      w2frag[f * 64 + tid] = make_uint4(w[0], w[1], w[2], w[3]);
    } else {
      b1p[tid] = b1[perm_col(tid)];
      if (tid == 0) {
        const uint32* raw = (const uint32*)eptr;
        int is64 = 1;
        for (int i = 0; i < 64; ++i)
          if (raw[2 * i + 1] != 0u) { is64 = 0; break; }
        *flag = is64;
      }
    }
    return;
  }
  // ---- passA body (edge block eb = bk - NWF) ----
  __shared__ int cnt[NBUCK];
  for (int i = tid; i < NBUCK; i += 256) cnt[i] = 0;
  // inline probe: every wave reads the same 64 high-words -> same verdict
  {
    const uint32* raw = (const uint32*)eptr;
    unsigned long long nz = __ballot(raw[2 * (tid & 63) + 1] != 0u);
    int is64 = (nz == 0ull);
    __syncthreads();
    int eb = bk - NWF;
    int base = eb * EPB;
#pragma unroll
    for (int k = 0; k < EPB / 256; ++k) {
      int e = base + k * 256 + tid;
      if (e < NE) {
        int d = is64 ? (int)((const long long*)eptr)[e + NE]
                     : ((const int*)eptr)[e + NE];
        atomicAdd(&cnt[d >> 8], 1);
      }
    }
    __syncthreads();
    for (int i = tid; i < NBUCK; i += 256)
      mat[eb * NBUCK + i] = cnt[i];
  }
}

// ---- passB1: per-bucket exclusive scan over blocks; emit bucket totals ----
__global__ __launch_bounds__(512) void passB1_kernel(int* __restrict__ mat,
                                                     int* __restrict__ tot) {
  __shared__ int s[512];
  int b = blockIdx.x;         // bucket
  int t = threadIdx.x;        // block index
  int v = (t < NEB) ? mat[t * NBUCK + b] : 0;
  s[t] = v;
  __syncthreads();
#pragma unroll
  for (int d = 1; d < 512; d <<= 1) {
    int u = (t >= d) ? s[t - d] : 0;
    __syncthreads();
    s[t] += u;
    __syncthreads();
  }
  if (t < NEB) mat[t * NBUCK + b] = s[t] - v;  // exclusive prefix within bucket
  if (t == 511) tot[b] = s[511];
}

// ---- passB2: exclusive scan of bucket totals -> bbase ----
__global__ __launch_bounds__(512) void passB2_kernel(const int* __restrict__ tot,
                                                     int* __restrict__ bbase) {
  __shared__ int s[512];
  int i = threadIdx.x;
  int v = (i < NBUCK) ? tot[i] : 0;
  s[i] = v;
  __syncthreads();
#pragma unroll
  for (int d = 1; d < 512; d <<= 1) {
    int u = (i >= d) ? s[i - d] : 0;
    __syncthreads();
    s[i] += u;
    __syncthreads();
  }
  if (i < NBUCK) bbase[i] = s[i] - v;
  if (i == 511) bbase[NBUCK] = s[511];
}

// ---- passC: place edges into compact bucket-sorted bbuf (LDS cursors) ----
__global__ __launch_bounds__(256) void passC_kernel(const void* __restrict__ eptr,
                                                    const int* __restrict__ flag,
                                                    const int* __restrict__ mat,
                                                    const int* __restrict__ bbase,
                                                    uint32* __restrict__ bbuf) {
  __shared__ int cur[NBUCK];
  int tid = threadIdx.x;
  for (int i = tid; i < NBUCK; i += 256)
    cur[i] = bbase[i] + mat[blockIdx.x * NBUCK + i];
  __syncthreads();
  int is64 = *flag;
  int base = blockIdx.x * EPB;
#pragma unroll
  for (int k = 0; k < EPB / 256; ++k) {
    int e = base + k * 256 + tid;
    if (e < NE) {
      int s, d;
      if (is64) {
        const long long* p = (const long long*)eptr;
        s = (int)p[e]; d = (int)p[e + NE];
      } else {
        const int* p = (const int*)eptr;
        s = p[e]; d = p[e + NE];
      }
      int slot = atomicAdd(&cur[d >> 8], 1);
      bbuf[slot] = (uint32)s | ((uint32)(d & 255) << 17);
    }
  }
}

// ---- build: per-bucket CSR (LDS hist + scan + rank placement) ----
__global__ __launch_bounds__(256) void build_kernel(const int* __restrict__ bbase,
                                                    const uint32* __restrict__ bbuf,
                                                    int* __restrict__ off,
                                                    float* __restrict__ dinv,
                                                    int* __restrict__ s_src) {
  __shared__ int hist[256];
  __shared__ int lofs[256];
  __shared__ int rank[256];
  int b = blockIdx.x, tid = threadIdx.x;
  int base = bbase[b];
  int count = bbase[b + 1] - base;
  const uint32* p = bbuf + base;
  hist[tid] = 0;
  __syncthreads();
  for (int i = tid; i < count; i += 256) atomicAdd(&hist[p[i] >> 17], 1);
  __syncthreads();
  int deg = hist[tid];
  lofs[tid] = deg;
  __syncthreads();
#pragma unroll
  for (int dd = 1; dd < 256; dd <<= 1) {
    int t = (tid >= dd) ? lofs[tid - dd] : 0;
    __syncthreads();
    lofs[tid] += t;
    __syncthreads();
  }
  int excl = lofs[tid] - deg;
  __syncthreads();
  lofs[tid] = excl;
  rank[tid] = 0;
  int n = b * 256 + tid;
  if (n < NN) {
    off[n] = base + excl;
    dinv[n] = rsqrtf((float)deg + 1.0f);
  }
  if (b == 0 && tid == 0) off[NN] = NE;
  __syncthreads();
  for (int i = tid; i < count; i += 256) {
    uint32 v = p[i];
    int dl = (int)(v >> 17);
    int s = (int)(v & 0x1FFFFu);
    int r = atomicAdd(&rank[dl], 1);
    s_src[base + lofs[dl] + r] = s;
  }
}

// ---- GEMM1 (MFMA): hs'[N,64](bf16, perm cols) = (x @ W1) * dinv[row] ----
// split-precision (xh*wh + xh*wl + xl*wh ~ fp32). 96 MFMAs/wave, no LDS.
__global__ __launch_bounds__(256) void gemm1_kernel(const float* __restrict__ x,
                                                    const uint4* __restrict__ wfrag,
                                                    const float* __restrict__ dinv,
                                                    uint32* __restrict__ hs) {
  int wid = blockIdx.x * 4 + (threadIdx.x >> 6);
  if (wid >= NN / 32) return;                 // 3125 waves exactly
  int lane = threadIdx.x & 63;
  int l15 = lane & 15, lg = lane >> 4;
  int r0 = wid * 32;
  f32x4 acc[2][4];
#pragma unroll
  for (int mr = 0; mr < 2; ++mr)
#pragma unroll
    for (int nr = 0; nr < 4; ++nr) acc[mr][nr] = (f32x4)0.f;
  const float4* x4 = (const float4*)x;
#pragma unroll
  for (int kr = 0; kr < 4; ++kr) {
    uint4 ah[2], al[2];
#pragma unroll
    for (int mr = 0; mr < 2; ++mr) {
      int m = r0 + mr * 16 + l15;
      int q0 = m * 32 + kr * 8 + lg * 2;
      float4 u = x4[q0], v = x4[q0 + 1];
      float xs[8] = {u.x, u.y, u.z, u.w, v.x, v.y, v.z, v.w};
      uint32 hw[4], lw[4];
#pragma unroll
      for (int j = 0; j < 4; ++j) {
        float a0 = xs[2 * j], a1 = xs[2 * j + 1];
        uint32 h0 = f2bf(a0), h1 = f2bf(a1);
        float ra = a0 - __uint_as_float(h0 << 16);
        float rb = a1 - __uint_as_float(h1 << 16);
        hw[j] = h0 | (h1 << 16);
        lw[j] = (uint32)f2bf(ra) | ((uint32)f2bf(rb) << 16);
      }
      ah[mr] = make_uint4(hw[0], hw[1], hw[2], hw[3]);
      al[mr] = make_uint4(lw[0], lw[1], lw[2], lw[3]);
    }
#pragma unroll
    for (int nr = 0; nr < 4; ++nr) {
      uint4 bh = wfrag[(kr * 4 + nr) * 64 + lane];
      uint4 bl = wfrag[((4 + kr) * 4 + nr) * 64 + lane];
#pragma unroll
      for (int mr = 0; mr < 2; ++mr) {
        acc[mr][nr] = mfma_bf16(ah[mr], bh, acc[mr][nr]);
        acc[mr][nr] = mfma_bf16(al[mr], bh, acc[mr][nr]);
        acc[mr][nr] = mfma_bf16(ah[mr], bl, acc[mr][nr]);
      }
    }
  }
#pragma unroll
  for (int mr = 0; mr < 2; ++mr) {
    int rb = r0 + mr * 16 + 4 * lg;
    float4 dv = *(const float4*)&dinv[rb];
#pragma unroll
    for (int a = 0; a < 2; ++a) {
#pragma unroll
      for (int j = 0; j < 4; ++j) {
        float d = (&dv.x)[j];
        uint32 wv = pack2(acc[mr][2 * a][j] * d, acc[mr][2 * a + 1][j] * d);
        hs[(size_t)(rb + j) * 32 + a * 16 + l15] = wv;
      }
    }
  }
}

// ---- agg1: wave = 8 nodes x 8 col-lanes; lane owns 8 cols of one node.
// Depth-4 gathers; no barrier. R6-proven structure. ----
__global__ __launch_bounds__(256) void agg1_kernel(const int* __restrict__ off,
                                                   const int* __restrict__ s_src,
                                                   const uint4* __restrict__ hs4,
                                                   const float* __restrict__ dinv,
                                                   const float* __restrict__ b1p,
                                                   uint4* __restrict__ g) {
  int tid = threadIdx.x;
  int n = blockIdx.x * 32 + (tid >> 3);
  int hc = tid & 7;
  int j0 = off[n], j1 = off[n + 1];
  float a[8];
  {
    uint4 v = hs4[(size_t)n * 8 + hc];    // self term
    a[0] = bf_lo(v.x); a[1] = bf_hi(v.x); a[2] = bf_lo(v.y); a[3] = bf_hi(v.y);
    a[4] = bf_lo(v.z); a[5] = bf_hi(v.z); a[6] = bf_lo(v.w); a[7] = bf_hi(v.w);
  }
  int j = j0;
  for (; j + 3 < j1; j += 4) {
    int s0 = s_src[j], s1 = s_src[j + 1], s2 = s_src[j + 2], s3 = s_src[j + 3];
    uint4 v0 = hs4[(size_t)s0 * 8 + hc];
    uint4 v1 = hs4[(size_t)s1 * 8 + hc];
    uint4 v2 = hs4[(size_t)s2 * 8 + hc];
    uint4 v3 = hs4[(size_t)s3 * 8 + hc];
    ACC8(v0); ACC8(v1); ACC8(v2); ACC8(v3);
  }
  for (; j < j1; ++j) {
    uint4 v0 = hs4[(size_t)s_src[j] * 8 + hc];
    ACC8(v0);
  }
  float di = dinv[n];
  float4 b0 = *(const float4*)&b1p[hc * 8];
  float4 b4 = *(const float4*)&b1p[hc * 8 + 4];
  float r0 = di * fmaxf(a[0] * di + b0.x, 0.f);
  float r1 = di * fmaxf(a[1] * di + b0.y, 0.f);
  float r2 = di * fmaxf(a[2] * di + b0.z, 0.f);
  float r3 = di * fmaxf(a[3] * di + b0.w, 0.f);
  float r4 = di * fmaxf(a[4] * di + b4.x, 0.f);
  float r5 = di * fmaxf(a[5] * di + b4.y, 0.f);
  float r6 = di * fmaxf(a[6] * di + b4.z, 0.f);
  float r7 = di * fmaxf(a[7] * di + b4.w, 0.f);
  uint4 o;
  o.x = pack2(r0, r1); o.y = pack2(r2, r3);
  o.z = pack2(r4, r5); o.w = pack2(r6, r7);
  g[(size_t)n * 8 + hc] = o;     // 8 lanes x 16B = 128B contiguous per node
}

// ---- gemm2: y[N,40](fp16) = g'[N,64](bf16, perm z) @ W2p (split hi/lo). ----
__global__ __launch_bounds__(256) void gemm2_kernel(const uint4* __restrict__ g4,
                                                    const uint4* __restrict__ w2frag,
                                                    unsigned short* __restrict__ y16) {
  int wid = blockIdx.x * 4 + (threadIdx.x >> 6);
  if (wid >= NN / 32) return;                 // 3125 waves
  int lane = threadIdx.x & 63;
  int l15 = lane & 15, lg = lane >> 4;
  int r0 = wid * 32;
  f32x4 acc[2][3];
#pragma unroll
  for (int mr = 0; mr < 2; ++mr)
#pragma unroll
    for (int nf = 0; nf < 3; ++nf) acc[mr][nf] = (f32x4)0.f;
#pragma unroll
  for (int kr = 0; kr < 2; ++kr) {
    uint4 a0 = g4[(size_t)(r0 + l15) * 8 + kr * 4 + lg];
    uint4 a1 = g4[(size_t)(r0 + 16 + l15) * 8 + kr * 4 + lg];
#pragma unroll
    for (int nf = 0; nf < 3; ++nf) {
      uint4 bh = w2frag[(kr * 3 + nf) * 64 + lane];          // t2=0 hi
      uint4 bl = w2frag[((2 + kr) * 3 + nf) * 64 + lane];    // t2=1 lo
      acc[0][nf] = mfma_bf16(a0, bh, acc[0][nf]);
      acc[0][nf] = mfma_bf16(a0, bl, acc[0][nf]);
      acc[1][nf] = mfma_bf16(a1, bh, acc[1][nf]);
      acc[1][nf] = mfma_bf16(a1, bl, acc[1][nf]);
    }
  }
#pragma unroll
  for (int mr = 0; mr < 2; ++mr) {
#pragma unroll
    for (int nf = 0; nf < 3; ++nf) {
      int col = nf * 16 + l15;
      if (col < NCLS) {
#pragma unroll
        for (int j = 0; j < 4; ++j) {
          int row = r0 + mr * 16 + 4 * lg + j;
          __half h = __float2half(acc[mr][nf][j]);
          y16[(size_t)row * NCLS + col] = __builtin_bit_cast(unsigned short, h);
        }
      }
    }
  }
}

// ---- agg2y: out[n] = dinv_n*(y[n] + sum_src y[src]) + b2. 5 lanes/node. ----
__global__ __launch_bounds__(256) void agg2y_kernel(const int* __restrict__ off,
                                                    const int* __restrict__ s_src,
                                                    const uint4* __restrict__ y4,
                                                    const float* __restrict__ dinv,
                                                    const float* __restrict__ b2,
                                                    float* __restrict__ out) {
  int T = blockIdx.x * 256 + threadIdx.x;
  int n = T / 5;
  int sub = T - n * 5;            // 16B chunk (8 of 40 fp16 cols)
  if (n >= NN) return;
  int j0 = off[n], j1 = off[n + 1];
  float a[8];
  {
    uint4 v = y4[(size_t)n * 5 + sub];   // self term
    float2 f0 = h2f2(v.x), f1 = h2f2(v.y), f2 = h2f2(v.z), f3 = h2f2(v.w);
    a[0] = f0.x; a[1] = f0.y; a[2] = f1.x; a[3] = f1.y;
    a[4] = f2.x; a[5] = f2.y; a[6] = f3.x; a[7] = f3.y;
  }
  int j = j0;
  for (; j + 3 < j1; j += 4) {
    int s0 = s_src[j], s1 = s_src[j + 1], s2 = s_src[j + 2], s3 = s_src[j + 3];
    uint4 v0 = y4[(size_t)s0 * 5 + sub];
    uint4 v1 = y4[(size_t)s1 * 5 + sub];
    uint4 v2 = y4[(size_t)s2 * 5 + sub];
    uint4 v3 = y4[(size_t)s3 * 5 + sub];
    ACC8H(v0); ACC8H(v1); ACC8H(v2); ACC8H(v3);
  }
  for (; j < j1; ++j) {
    uint4 v0 = y4[(size_t)s_src[j] * 5 + sub];
    ACC8H(v0);
  }
  float di = dinv[n];
  int c0 = sub * 8;
  float4 bb0 = *(const float4*)&b2[c0];
  float4 bb1 = *(const float4*)&b2[c0 + 4];
  float* op = &out[(size_t)n * NCLS + c0];
  *(float4*)op = make_float4(a[0] * di + bb0.x, a[1] * di + bb0.y,
                             a[2] * di + bb0.z, a[3] * di + bb0.w);
  *(float4*)(op + 4) = make_float4(a[4] * di + bb1.x, a[5] * di + bb1.y,
                                   a[6] * di + bb1.z, a[7] * di + bb1.w);
}

extern "C" void kernel_launch(void* const* d_in, const int* in_sizes, int n_in,
                              void* d_out, int out_size, void* d_ws, size_t ws_size,
                              hipStream_t stream) {
  const float* x  = (const float*)d_in[0];
  const void*  ei = d_in[1];
  const float* W1 = (const float*)d_in[2];
  const float* b1 = (const float*)d_in[3];
  const float* W2 = (const float*)d_in[4];
  const float* b2 = (const float*)d_in[5];
  float* out = (float*)d_out;

  char* w = (char*)d_ws;
  size_t off_b = 0;
  auto carve = [&](size_t bytes) -> void* {
    void* p = w + off_b;
    off_b = (off_b + bytes + 255) & ~(size_t)255;
    return p;
  };
  int*    mat    = (int*)   carve((size_t)NEB * NBUCK * 4);   // 611 KB
  int*    tot    = (int*)   carve((size_t)NBUCK * 4);
  int*    bbase  = (int*)   carve((size_t)(NBUCK + 1) * 4);
  int*    offs   = (int*)   carve((size_t)(NN + 1) * 4);
  float*  dinv   = (float*) carve((size_t)NN * 4);
  int*    flag   = (int*)   carve(256);
  int*    s_src  = (int*)   carve((size_t)NE * 4);
  uint32* hs     = (uint32*)carve((size_t)NN * 32 * 4);       // bf16 h, 12.8 MB
  uint4*  g      = (uint4*) carve((size_t)NN * 8 * 16);       // bf16 g, 12.8 MB
  uint32* bbuf   = (uint32*)carve((size_t)NE * 4);            // 6.4 MB
  uint4*  wfrag  = (uint4*) carve((size_t)2048 * 16);         // 32 KB
  uint4*  w2frag = (uint4*) carve((size_t)768 * 16);          // 12 KB
  float*  b1p    = (float*) carve((size_t)HIDN * 4);          // 256 B
  unsigned short* y16 = (unsigned short*)carve((size_t)NN * NCLS * 2);  // 8 MB

  passAW_kernel<<<NWF + NEB, 256, 0, stream>>>(W1, b1, W2, ei, wfrag, w2frag,
                                               b1p, flag, mat);
  passB1_kernel<<<NBUCK, 512, 0, stream>>>(mat, tot);
  passB2_kernel<<<1, 512, 0, stream>>>(tot, bbase);
  passC_kernel<<<NEB, 256, 0, stream>>>(ei, flag, mat, bbase, bbuf);
  build_kernel<<<NBUCK, 256, 0, stream>>>(bbase, bbuf, offs, dinv, s_src);
  gemm1_kernel<<<(NN / 32 + 3) / 4, 256, 0, stream>>>(x, wfrag, dinv, hs);
  agg1_kernel<<<NN / 32, 256, 0, stream>>>(offs, s_src, (const uint4*)hs, dinv, b1p, g);
  gemm2_kernel<<<(NN / 32 + 3) / 4, 256, 0, stream>>>(g, w2frag, y16);
  agg2y_kernel<<<(NN * 5 + 255) / 256, 256, 0, stream>>>(offs, s_src,
                                                         (const uint4*)y16, dinv, b2, out);
}